// Round 9
// baseline (241.091 us; speedup 1.0000x reference)
//
#include <hip/hip_runtime.h>
#include <math.h>

#define N_NODES 4096
#define T_LEN 1000
#define TCH 16
#define AHD 32
#define F3D 48
#define GCD 32
#define NPG 64
#define NGRAPH 64
#define BN_EPS 1e-5f

typedef _Float16 half4_t __attribute__((ext_vector_type(4)));
typedef __fp16 fp16x2 __attribute__((ext_vector_type(2)));
typedef float float4_t __attribute__((ext_vector_type(4)));

__device__ __forceinline__ float fast_rcp(float x){ return __builtin_amdgcn_rcpf(x); }
__device__ __forceinline__ float gelu_exact(float v){
    return 0.5f*v*(1.0f+erff(v*0.70710678118654752f));
}

struct BranchParams {
    const float* conv_w; const float* conv_b;
    const float* bn_g; const float* bn_b; const float* bn_m; const float* bn_v;
    const float* aw1; const float* ab1; const float* aw2; const float* ab2;
    int K; int col0;
};

// ---------------------------------------------------------------------------
// Unified branch kernel: conv-as-MFMA -> sigmoid-form GELU (quad-shared rcp)
// -> einsum MFMA with 2*log2e prefolded -> exp2-tanh (quad-shared rcp)
// -> block softmax (no max-sub; exp2 domain) -> register weighted pool.
// ---------------------------------------------------------------------------
__global__ __launch_bounds__(256)
void branch_kernel(const float* __restrict__ x,
                   BranchParams bp0, BranchParams bp1, BranchParams bp2,
                   float* __restrict__ xf, float* __restrict__ colacc)
{
    __shared__ __align__(16) float xs_f[1060];
    __shared__ __align__(8)  _Float16 xsc[4][1060];  // 4 shift-staggered fp16 copies
    __shared__ __align__(8)  _Float16 cws16[256];
    __shared__ float s_arr[1024];
    __shared__ __align__(16) float shiftc[16];
    __shared__ float scl[16];
    __shared__ float reds[4];
    __shared__ __align__(16) float fredw[4][16];

    const BranchParams bp = (blockIdx.y==0)? bp0 : (blockIdx.y==1)? bp1 : bp2;
    const int tid = threadIdx.x;
    const int node = blockIdx.x;
    const int K = bp.K;
    const float* xrow = x + (size_t)node*T_LEN;

    for (int j=tid;j<1060;j+=256){
        int q = j-8;
        xs_f[j] = (q>=0 && q<T_LEN)? xrow[q] : 0.f;
    }
    if (tid<16){
        float s = bp.bn_g[tid]*rsqrtf(bp.bn_v[tid]+BN_EPS);
        scl[tid]=s;
        shiftc[tid] = (bp.conv_b[tid]-bp.bn_m[tid])*s + bp.bn_b[tid];
    }
    __syncthreads();
    // paired half2 writes of the 4 shifted fp16 copies
    for (int j2=2*tid; j2<1056; j2+=512){
        float v0=xs_f[j2],v1=xs_f[j2+1],v2=xs_f[j2+2],v3=xs_f[j2+3],v4=xs_f[j2+4];
        *(fp16x2*)&xsc[0][j2] = __builtin_amdgcn_cvt_pkrtz(v0,v1);
        *(fp16x2*)&xsc[1][j2] = __builtin_amdgcn_cvt_pkrtz(v1,v2);
        *(fp16x2*)&xsc[2][j2] = __builtin_amdgcn_cvt_pkrtz(v2,v3);
        *(fp16x2*)&xsc[3][j2] = __builtin_amdgcn_cvt_pkrtz(v3,v4);
    }
    {
        int ch=tid>>4, tap=tid&15;
        cws16[tid] = (tap<K)? (_Float16)(bp.conv_w[ch*K+tap]*scl[ch]) : (_Float16)0.f;
    }
    __syncthreads();

    const int lane = tid&63, wave = tid>>6;
    const int col  = lane&15;
    const int kg   = (lane>>4)<<2;

    const half4_t  acw = *(const half4_t*)&cws16[col*16+kg];
    const float4_t csh = *(const float4_t*)&shiftc[kg];

    const float TWO_LOG2E = 2.8853900817779268f;
    const float LOG2E = 1.4426950408889634f;

    float4_t wr0 = *(const float4_t*)&bp.aw1[(size_t)col*TCH + kg];
    float4_t wr1 = *(const float4_t*)&bp.aw1[(size_t)(col+16)*TCH + kg];
    half4_t a0,a1;
    #pragma unroll
    for (int r=0;r<4;r++){ a0[r]=(_Float16)(wr0[r]*TWO_LOG2E); a1[r]=(_Float16)(wr1[r]*TWO_LOG2E); }
    float4_t c0  = *(const float4_t*)&bp.ab1[kg];
    float4_t c1  = *(const float4_t*)&bp.ab1[16+kg];
    #pragma unroll
    for (int r=0;r<4;r++){ c0[r]*=TWO_LOG2E; c1[r]*=TWO_LOG2E; }
    float4_t w20 = *(const float4_t*)&bp.aw2[kg];
    float4_t w21 = *(const float4_t*)&bp.aw2[16+kg];
    #pragma unroll
    for (int r=0;r<4;r++){ w20[r]*=LOG2E; w21[r]*=LOG2E; }
    const float b2v = bp.ab2[0]*LOG2E;
    const float w2sum8 = w20[0]+w20[1]+w20[2]+w20[3]+w21[0]+w21[1]+w21[2]+w21[3];

    const float C1GE = -2.30220818f;
    const float C2GE = -0.10294324f;

    const int abase = 8 + wave*256 + col + kg - K/2;
    const int sh = abase & 3;
    const _Float16* xw_base = &xsc[sh][abase - sh];

    half4_t oreg[16];
    #pragma unroll
    for (int i=0;i<16;i++){
        half4_t xw = *(const half4_t*)(xw_base + i*16);
        float4_t d = __builtin_amdgcn_mfma_f32_16x16x16f16(acw, xw, csh, 0,0,0);

        // GELU (sigmoid form), clamp -6; quad-shared reciprocal.
        // Quad product can only overflow when all four v <= -4.5, where all
        // four outputs are correctly ~0.
        float vv[4], dd[4];
        #pragma unroll
        for (int r=0;r<4;r++){
            float v = d[r];
            vv[r] = v;
            float t = fmaxf(v, -6.0f);
            float u = t*t;
            float pq = fmaf(C2GE, u, C1GE);
            dd[r] = __builtin_amdgcn_exp2f(pq*t) + 1.0f;
        }
        union { half4_t h4; fp16x2 h2[2]; } obu;
        {
            float p0 = dd[0]*dd[1], p1 = dd[2]*dd[3];
            float R  = fast_rcp(p0*p1);
            float q0 = p1*R, q1 = p0*R;     // 1/(dd0*dd1), 1/(dd2*dd3)
            obu.h2[0] = __builtin_amdgcn_cvt_pkrtz(vv[0]*(dd[1]*q0), vv[1]*(dd[0]*q0));
            obu.h2[1] = __builtin_amdgcn_cvt_pkrtz(vv[2]*(dd[3]*q1), vv[3]*(dd[2]*q1));
        }
        const half4_t ob = obu.h4;
        oreg[i] = ob;

        float4_t h0 = __builtin_amdgcn_mfma_f32_16x16x16f16(a0, ob, c0, 0,0,0);
        float4_t h1 = __builtin_amdgcn_mfma_f32_16x16x16f16(a1, ob, c1, 0,0,0);
        // sum w2*tanh: w2sum8 - 2*sum w2/(exp2(h')+1), quad-shared rcp
        float accr = 0.f;
        #pragma unroll
        for (int r=0;r<4;r+=2){
            float eA0 = __builtin_amdgcn_exp2f(h0[r])   + 1.0f;
            float eB0 = __builtin_amdgcn_exp2f(h1[r])   + 1.0f;
            float eA1 = __builtin_amdgcn_exp2f(h0[r+1]) + 1.0f;
            float eB1 = __builtin_amdgcn_exp2f(h1[r+1]) + 1.0f;
            float pA = eA0*eB0, pB = eA1*eB1;
            float R  = fast_rcp(pA*pB);
            float qA = pB*R, qB = pA*R;      // 1/pA, 1/pB
            accr = fmaf(w20[r],   eB0*qA, accr);
            accr = fmaf(w21[r],   eA0*qA, accr);
            accr = fmaf(w20[r+1], eB1*qB, accr);
            accr = fmaf(w21[r+1], eA1*qB, accr);
        }
        float part = fmaf(-2.0f, accr, w2sum8);
        part += __shfl_xor(part,16);
        part += __shfl_xor(part,32);
        const int pos0 = wave*256 + i*16;
        if (lane<16) s_arr[pos0+lane] = (pos0+lane < T_LEN)? (part + b2v) : -INFINITY;
    }
    __syncthreads();

    // block softmax over 1000 positions, no max-sub (scores bounded, exp2 domain)
    float sv[4];
    #pragma unroll
    for (int ii=0;ii<4;ii++) sv[ii]=s_arr[tid+ii*256];
    float e[4]; float ls=0.f;
    #pragma unroll
    for (int ii=0;ii<4;ii++){ e[ii]=__builtin_amdgcn_exp2f(sv[ii]); ls+=e[ii]; }
    #pragma unroll
    for (int off=32;off;off>>=1) ls += __shfl_xor(ls,off);
    if (lane==0) reds[wave]=ls;
    __syncthreads();
    const float invS = fast_rcp(reds[0]+reds[1]+reds[2]+reds[3]);
    #pragma unroll
    for (int ii=0;ii<4;ii++) s_arr[tid+ii*256]=e[ii];
    __syncthreads();

    float4_t acc = {0.f,0.f,0.f,0.f};
    #pragma unroll
    for (int i=0;i<16;i++){
        float ev = s_arr[wave*256 + i*16 + col];
        half4_t ob = oreg[i];
        #pragma unroll
        for (int r=0;r<4;r++) acc[r] += (float)ob[r]*ev;
    }
    #pragma unroll
    for (int off=1;off<16;off<<=1){
        #pragma unroll
        for (int r=0;r<4;r++) acc[r] += __shfl_xor(acc[r], off);
    }
    if (col==0) *(float4_t*)&fredw[wave][kg] = acc;
    __syncthreads();
    if (tid<16){
        float v = (fredw[0][tid]+fredw[1][tid]+fredw[2][tid]+fredw[3][tid])*invS;
        xf[(size_t)node*F3D + bp.col0 + tid] = v;
        atomicAdd(&colacc[bp.col0 + tid], v);
    }
}

// ---------------------------------------------------------------------------
// Local CSR build (edge pattern shared across the 64 graphs)
// ---------------------------------------------------------------------------
__global__ __launch_bounds__(128)
void csr_local_kernel(const int* __restrict__ ei, int epg,
                      int* __restrict__ rowstart, int* __restrict__ cols){
    __shared__ int deg[64], cur[64], rs[65];
    const int tid = threadIdx.x;
    if (tid<64) deg[tid]=0;
    __syncthreads();
    const int total = epg + 64;
    for (int e=tid;e<total;e+=128){
        int d = (e<epg)? ei[epg+e] : (e-epg);
        atomicAdd(&deg[d],1);
    }
    __syncthreads();
    if (tid<64){
        int v = deg[tid];
        int s = v;
        #pragma unroll
        for (int off=1;off<64;off<<=1){
            int t = __shfl_up(s, off);
            if (tid >= off) s += t;
        }
        rs[tid+1] = s;
        if (tid==0) rs[0]=0;
        cur[tid] = s - v;
    }
    __syncthreads();
    for (int e=tid;e<total;e+=128){
        int sN,dN;
        if (e<epg){ sN=ei[e]; dN=ei[epg+e]; } else { sN=dN=e-epg; }
        int pos = atomicAdd(&cur[dN],1);
        cols[pos]=sN;
    }
    if (tid<65) rowstart[tid]=rs[tid];
}

// ---------------------------------------------------------------------------
// GAT layer-1 node transform; SE gate recomputed in-block from column sums.
// ---------------------------------------------------------------------------
__global__ __launch_bounds__(128)
void gat_h1_kernel(const float* __restrict__ xf, const float* __restrict__ colacc,
                   const float* __restrict__ se_w1, const float* __restrict__ se_b1,
                   const float* __restrict__ se_w2, const float* __restrict__ se_b2,
                   const float* __restrict__ W,
                   const float* __restrict__ a_src, const float* __restrict__ a_dst,
                   float* __restrict__ hbuf, float* __restrict__ als, float* __restrict__ ald){
    __shared__ float cm[F3D];
    __shared__ float g1[12];
    __shared__ float xin[F3D];
    __shared__ float hs[128];
    const int node=blockIdx.x, tid=threadIdx.x;
    if (tid<F3D) cm[tid]=colacc[tid]*(1.0f/(float)N_NODES);
    __syncthreads();
    if (tid<12){
        float v=se_b1[tid];
        for (int j=0;j<F3D;j++) v += se_w1[tid*F3D+j]*cm[j];
        g1[tid]=gelu_exact(v);
    }
    __syncthreads();
    if (tid<F3D){
        float v=se_b2[tid];
        for (int m2=0;m2<12;m2++) v += se_w2[tid*12+m2]*g1[m2];
        xin[tid] = xf[(size_t)node*F3D+tid]*fast_rcp(1.0f+__expf(-v));
    }
    __syncthreads();
    float acc=0.f;
    const float* wr = W + (size_t)tid*F3D;
    #pragma unroll
    for (int j=0;j<F3D;j++) acc += wr[j]*xin[j];
    hs[tid]=acc;
    hbuf[(size_t)node*128+tid]=acc;
    __syncthreads();
    if (tid<8){
        int head=tid&3;
        const float* av = (tid<4)? a_src : a_dst;
        float s=0.f;
        for (int c=0;c<GCD;c++) s += hs[head*GCD+c]*av[head*GCD+c];
        if (tid<4) als[(size_t)node*4+head]=s;
        else       ald[(size_t)node*4+head]=s;
    }
}

// ---------------------------------------------------------------------------
// Fused GAT tail: gather1 + gat_h2 + logits2 + gather2 + pool + FC.
// One block per graph (64 nodes); local CSR; gate recomputed in-block.
// ---------------------------------------------------------------------------
__global__ __launch_bounds__(512)
void gat_tail_kernel(const int* __restrict__ rowstart, const int* __restrict__ cols,
                     const float* __restrict__ als, const float* __restrict__ ald,
                     const float* __restrict__ hbuf,
                     const float* __restrict__ bias1,
                     const float* __restrict__ bn1_g, const float* __restrict__ bn1_b,
                     const float* __restrict__ bn1_m, const float* __restrict__ bn1_v,
                     const float* __restrict__ xf, const float* __restrict__ colacc,
                     const float* __restrict__ se_w1, const float* __restrict__ se_b1,
                     const float* __restrict__ se_w2, const float* __restrict__ se_b2,
                     const float* __restrict__ skip_w, const float* __restrict__ skip_b,
                     const float* __restrict__ W2,
                     const float* __restrict__ asrc2, const float* __restrict__ adst2,
                     const float* __restrict__ bias2,
                     const float* __restrict__ bn2_g, const float* __restrict__ bn2_b,
                     const float* __restrict__ bn2_m, const float* __restrict__ bn2_v,
                     const float* __restrict__ fc_w, const float* __restrict__ fc_b,
                     float* __restrict__ out)
{
    __shared__ float hb[64*128];
    __shared__ float xh[64*48];
    __shared__ float h1l[64*32];
    __shared__ float a1s[256], a1d[256], a2s[256], a2d[256];
    __shared__ float skw[32*48];
    __shared__ float poolv[32];
    __shared__ float cm[F3D], g1[12], gate_sh[F3D];

    const int g = blockIdx.x;
    const int tid = threadIdx.x;
    const int n0 = g*NPG;

    if (tid<F3D) cm[tid]=colacc[tid]*(1.0f/(float)N_NODES);
    __syncthreads();
    if (tid<12){
        float v=se_b1[tid];
        for (int j=0;j<F3D;j++) v += se_w1[tid*F3D+j]*cm[j];
        g1[tid]=gelu_exact(v);
    }
    __syncthreads();
    if (tid<F3D){
        float v=se_b2[tid];
        for (int m2=0;m2<12;m2++) v += se_w2[tid*12+m2]*g1[m2];
        gate_sh[tid]=fast_rcp(1.0f+__expf(-v));
    }
    __syncthreads();

    for (int i=tid;i<64*128;i+=512) hb[i] = hbuf[(size_t)n0*128 + i];
    for (int i=tid;i<64*48;i+=512)  xh[i] = xf[(size_t)n0*F3D + i] * gate_sh[i%F3D];
    for (int i=tid;i<32*48;i+=512)  skw[i] = skip_w[i];
    if (tid<256){ a1s[tid]=als[n0*4+tid]; a1d[tid]=ald[n0*4+tid]; }
    __syncthreads();

    for (int p=0;p<4;p++){
        const int nl = p*16 + (tid>>5);
        const int c  = tid&31;
        const float4 ad = *(const float4*)&a1d[nl*4];
        float m0=0,m1=0,m2=0,m3=0,d0=0,d1=0,d2=0,d3=0;
        const int s0=rowstart[nl], s1=rowstart[nl+1];
        for (int e=s0;e<s1;e++){
            const int sl = cols[e];
            const float4 as=*(const float4*)&a1s[sl*4];
            float e0=as.x+ad.x; e0=e0>0.f?e0:0.2f*e0; float w0=__expf(e0);
            float e1=as.y+ad.y; e1=e1>0.f?e1:0.2f*e1; float w1=__expf(e1);
            float e2=as.z+ad.z; e2=e2>0.f?e2:0.2f*e2; float w2=__expf(e2);
            float e3=as.w+ad.w; e3=e3>0.f?e3:0.2f*e3; float w3=__expf(e3);
            const float* hr=&hb[sl*128];
            m0+=w0*hr[c]; m1+=w1*hr[32+c]; m2+=w2*hr[64+c]; m3+=w3*hr[96+c];
            d0+=w0; d1+=w1; d2+=w2; d3+=w3;
        }
        float acc = 0.25f*(m0*fast_rcp(d0)+m1*fast_rcp(d1)+m2*fast_rcp(d2)+m3*fast_rcp(d3)) + bias1[c];
        acc = (acc-bn1_m[c])*rsqrtf(bn1_v[c]+BN_EPS)*bn1_g[c]+bn1_b[c];
        float sk = skip_b[c];
        const float* xr=&xh[nl*F3D];
        #pragma unroll
        for (int j=0;j<F3D;j++) sk += xr[j]*skw[c*F3D+j];
        h1l[nl*32+c]=gelu_exact(acc+sk);
    }
    __syncthreads();

    for (int i=tid;i<64*128;i+=512){
        const int nl=i>>7, r=i&127;
        const float4* h1r=(const float4*)&h1l[nl*32];
        const float4* wr =(const float4*)&W2[r*32];
        float acc=0.f;
        #pragma unroll
        for (int j=0;j<8;j++){
            float4 a=h1r[j], b=wr[j];
            acc += a.x*b.x + a.y*b.y + a.z*b.z + a.w*b.w;
        }
        hb[i]=acc;
    }
    __syncthreads();

    {
        const int which = tid>>8;
        const int idx = tid&255;
        const int nl=idx>>2, h=idx&3;
        const float* av = which? &adst2[h*32] : &asrc2[h*32];
        const float* hr = &hb[nl*128 + h*32];
        float s=0.f;
        #pragma unroll
        for (int c=0;c<32;c++) s += hr[c]*av[c];
        if (which) a2d[idx]=s; else a2s[idx]=s;
    }
    __syncthreads();

    for (int p=0;p<4;p++){
        const int nl = p*16 + (tid>>5);
        const int c  = tid&31;
        const float4 ad = *(const float4*)&a2d[nl*4];
        float m0=0,m1=0,m2=0,m3=0,d0=0,d1=0,d2=0,d3=0;
        const int s0=rowstart[nl], s1=rowstart[nl+1];
        for (int e=s0;e<s1;e++){
            const int sl = cols[e];
            const float4 as=*(const float4*)&a2s[sl*4];
            float e0=as.x+ad.x; e0=e0>0.f?e0:0.2f*e0; float w0=__expf(e0);
            float e1=as.y+ad.y; e1=e1>0.f?e1:0.2f*e1; float w1=__expf(e1);
            float e2=as.z+ad.z; e2=e2>0.f?e2:0.2f*e2; float w2=__expf(e2);
            float e3=as.w+ad.w; e3=e3>0.f?e3:0.2f*e3; float w3=__expf(e3);
            const float* hr=&hb[sl*128];
            m0+=w0*hr[c]; m1+=w1*hr[32+c]; m2+=w2*hr[64+c]; m3+=w3*hr[96+c];
            d0+=w0; d1+=w1; d2+=w2; d3+=w3;
        }
        float acc = 0.25f*(m0*fast_rcp(d0)+m1*fast_rcp(d1)+m2*fast_rcp(d2)+m3*fast_rcp(d3)) + bias2[c];
        acc = (acc-bn2_m[c])*rsqrtf(bn2_v[c]+BN_EPS)*bn2_g[c]+bn2_b[c];
        float v = acc + h1l[nl*32+c];
        xh[nl*32+c]=gelu_exact(v);
    }
    __syncthreads();

    if (tid<32){
        float s=0.f;
        for (int n=0;n<NPG;n++) s += xh[n*32+tid];
        poolv[tid]=s*(1.0f/(float)NPG);
    }
    __syncthreads();
    if (tid<2){
        float o=fc_b[tid];
        #pragma unroll
        for (int c=0;c<GCD;c++) o += poolv[c]*fc_w[tid*GCD+c];
        out[g*2+tid]=o;
    }
}

// ---------------------------------------------------------------------------
extern "C" void kernel_launch(void* const* d_in, const int* in_sizes, int n_in,
                              void* d_out, int out_size, void* d_ws, size_t ws_size,
                              hipStream_t stream){
    const float* x = (const float*)d_in[0];
    const int* ei = (const int*)d_in[1];
    const int epg = in_sizes[1]/2;

    float* ws = (float*)d_ws;
    float* xf      = ws;                                   // [4096,48]
    float* colacc  = xf + (size_t)N_NODES*F3D;             // 64
    float* hbuf    = colacc + 64;                          // [4096,128]
    float* als     = hbuf + (size_t)N_NODES*128;           // [4096,4]
    float* ald     = als + (size_t)N_NODES*4;              // [4096,4]
    int*   rowstart = (int*)(ald + (size_t)N_NODES*4);     // [65]
    int*   cols     = rowstart + 80;                       // [epg+64]

    auto P = [&](int i){ return (const float*)d_in[i]; };

    (void)hipMemsetAsync(colacc, 0, 64*sizeof(float), stream);
    csr_local_kernel<<<1,128,0,stream>>>(ei,epg,rowstart,cols);

    BranchParams bps[3];
    const int Ks[3] = {3,5,7};
    for (int b=0;b<3;b++){
        int base = 2 + b*10;
        bps[b].conv_w = P(base+0); bps[b].conv_b = P(base+1);
        bps[b].bn_g = P(base+2);   bps[b].bn_b = P(base+3);
        bps[b].bn_m = P(base+4);   bps[b].bn_v = P(base+5);
        bps[b].aw1 = P(base+6);    bps[b].ab1 = P(base+7);
        bps[b].aw2 = P(base+8);    bps[b].ab2 = P(base+9);
        bps[b].K = Ks[b]; bps[b].col0 = b*TCH;
    }
    branch_kernel<<<dim3(N_NODES,3),256,0,stream>>>(x, bps[0], bps[1], bps[2], xf, colacc);

    gat_h1_kernel<<<N_NODES,128,0,stream>>>(xf,colacc,P(32),P(33),P(34),P(35),
                                            P(36),P(37),P(38),hbuf,als,ald);

    gat_tail_kernel<<<NGRAPH,512,0,stream>>>(
        rowstart,cols,als,ald,hbuf,
        P(39),P(40),P(41),P(42),P(43),
        xf,colacc,P(32),P(33),P(34),P(35),
        P(44),P(45),
        P(46),P(47),P(48),P(49),P(50),P(51),P(52),P(53),
        P(54),P(55),(float*)d_out);
}

// Round 10
// 238.265 us; speedup vs baseline: 1.0119x; 1.0119x over previous
//
#include <hip/hip_runtime.h>
#include <math.h>

#define N_NODES 4096
#define T_LEN 1000
#define TCH 16
#define AHD 32
#define F3D 48
#define GCD 32
#define NPG 64
#define NGRAPH 64
#define BN_EPS 1e-5f

typedef _Float16 half4_t __attribute__((ext_vector_type(4)));
typedef float float4_t __attribute__((ext_vector_type(4)));

__device__ __forceinline__ float fast_rcp(float x){ return __builtin_amdgcn_rcpf(x); }
__device__ __forceinline__ float gelu_exact(float v){
    return 0.5f*v*(1.0f+erff(v*0.70710678118654752f));
}

struct BranchParams {
    const float* conv_w; const float* conv_b;
    const float* bn_g; const float* bn_b; const float* bn_m; const float* bn_v;
    const float* aw1; const float* ab1; const float* aw2; const float* ab2;
    int K; int col0;
};

// ---------------------------------------------------------------------------
// Unified branch kernel (round-7 best config) + packed-fp16 weighted pool.
// conv-as-MFMA -> sigmoid-form GELU (pair-shared rcp) -> einsum MFMA with
// 2*log2e prefolded -> exp2-tanh (pair-shared rcp) -> block softmax (no
// max-sub; exp2 domain) -> packed-fp16 register pool.
// ---------------------------------------------------------------------------
__global__ __launch_bounds__(256)
void branch_kernel(const float* __restrict__ x,
                   BranchParams bp0, BranchParams bp1, BranchParams bp2,
                   float* __restrict__ xf, float* __restrict__ colacc)
{
    __shared__ __align__(16) float xs_f[1056];
    __shared__ __align__(8)  _Float16 xsc[4][1048];  // 4 shift-staggered fp16 copies
    __shared__ __align__(8)  _Float16 cws16[256];
    __shared__ float s_arr[1024];
    __shared__ __align__(16) float shiftc[16];
    __shared__ float scl[16];
    __shared__ float reds[4];
    __shared__ __align__(16) float fredw[4][16];

    const BranchParams bp = (blockIdx.y==0)? bp0 : (blockIdx.y==1)? bp1 : bp2;
    const int tid = threadIdx.x;
    const int node = blockIdx.x;
    const int K = bp.K;
    const float* xrow = x + (size_t)node*T_LEN;

    for (int j=tid;j<1056;j+=256){
        int q = j-8;
        xs_f[j] = (q>=0 && q<T_LEN)? xrow[q] : 0.f;
    }
    if (tid<16){
        float s = bp.bn_g[tid]*rsqrtf(bp.bn_v[tid]+BN_EPS);
        scl[tid]=s;
        shiftc[tid] = (bp.conv_b[tid]-bp.bn_m[tid])*s + bp.bn_b[tid];
    }
    __syncthreads();
    for (int j=tid;j<1048;j+=256){
        xsc[0][j]=(_Float16)xs_f[j];
        xsc[1][j]=(_Float16)xs_f[j+1];
        xsc[2][j]=(_Float16)xs_f[j+2];
        xsc[3][j]=(_Float16)xs_f[j+3];
    }
    {
        int ch=tid>>4, tap=tid&15;
        cws16[tid] = (tap<K)? (_Float16)(bp.conv_w[ch*K+tap]*scl[ch]) : (_Float16)0.f;
    }
    __syncthreads();

    const int lane = tid&63, wave = tid>>6;
    const int col  = lane&15;
    const int kg   = (lane>>4)<<2;

    const half4_t  acw = *(const half4_t*)&cws16[col*16+kg];
    const float4_t csh = *(const float4_t*)&shiftc[kg];

    const float TWO_LOG2E = 2.8853900817779268f;
    const float LOG2E = 1.4426950408889634f;

    float4_t wr0 = *(const float4_t*)&bp.aw1[(size_t)col*TCH + kg];
    float4_t wr1 = *(const float4_t*)&bp.aw1[(size_t)(col+16)*TCH + kg];
    half4_t a0,a1;
    #pragma unroll
    for (int r=0;r<4;r++){ a0[r]=(_Float16)(wr0[r]*TWO_LOG2E); a1[r]=(_Float16)(wr1[r]*TWO_LOG2E); }
    float4_t c0  = *(const float4_t*)&bp.ab1[kg];
    float4_t c1  = *(const float4_t*)&bp.ab1[16+kg];
    #pragma unroll
    for (int r=0;r<4;r++){ c0[r]*=TWO_LOG2E; c1[r]*=TWO_LOG2E; }
    float4_t w20 = *(const float4_t*)&bp.aw2[kg];
    float4_t w21 = *(const float4_t*)&bp.aw2[16+kg];
    #pragma unroll
    for (int r=0;r<4;r++){ w20[r]*=LOG2E; w21[r]*=LOG2E; }
    const float b2v = bp.ab2[0]*LOG2E;
    const float w2sum8 = w20[0]+w20[1]+w20[2]+w20[3]+w21[0]+w21[1]+w21[2]+w21[3];

    const float C1GE = -2.30220818f;
    const float C2GE = -0.10294324f;

    const int abase = 8 + wave*256 + col + kg - K/2;
    const int sh = abase & 3;
    const _Float16* xw_base = &xsc[sh][abase - sh];

    half4_t oreg[16];
    #pragma unroll
    for (int i=0;i<16;i++){
        half4_t xw = *(const half4_t*)(xw_base + i*16);
        float4_t d = __builtin_amdgcn_mfma_f32_16x16x16f16(acw, xw, csh, 0,0,0);

        // GELU (sigmoid form), exp2-clamped at v=-9 so dd stays finite
        float vv[4], dd[4];
        #pragma unroll
        for (int r=0;r<4;r++){
            float v = d[r];
            vv[r] = v;
            float t = fmaxf(v, -9.0f);
            float u = t*t;
            float pq = fmaf(C2GE, u, C1GE);
            dd[r] = __builtin_amdgcn_exp2f(pq*t) + 1.0f;
        }
        half4_t ob;
        {
            float rp0 = fast_rcp(dd[0]*dd[1]);
            float rp1 = fast_rcp(dd[2]*dd[3]);
            ob[0] = (_Float16)(vv[0]*(dd[1]*rp0));
            ob[1] = (_Float16)(vv[1]*(dd[0]*rp0));
            ob[2] = (_Float16)(vv[2]*(dd[3]*rp1));
            ob[3] = (_Float16)(vv[3]*(dd[2]*rp1));
        }
        oreg[i] = ob;

        float4_t h0 = __builtin_amdgcn_mfma_f32_16x16x16f16(a0, ob, c0, 0,0,0);
        float4_t h1 = __builtin_amdgcn_mfma_f32_16x16x16f16(a1, ob, c1, 0,0,0);
        // sum w2*tanh: w2sum8 - 2*sum w2/(exp2(h')+1), pair-shared rcp
        float accr = 0.f;
        #pragma unroll
        for (int r=0;r<4;r++){
            float e0 = __builtin_amdgcn_exp2f(h0[r]) + 1.0f;
            float e1 = __builtin_amdgcn_exp2f(h1[r]) + 1.0f;
            float rp = fast_rcp(e0*e1);
            accr = fmaf(w20[r], e1*rp, accr);
            accr = fmaf(w21[r], e0*rp, accr);
        }
        float part = fmaf(-2.0f, accr, w2sum8);
        part += __shfl_xor(part,16);
        part += __shfl_xor(part,32);
        const int pos0 = wave*256 + i*16;
        if (lane<16) s_arr[pos0+lane] = (pos0+lane < T_LEN)? (part + b2v) : -INFINITY;
    }
    __syncthreads();

    // block softmax over 1000 positions, no max-sub (scores bounded, exp2 domain)
    float sv[4];
    #pragma unroll
    for (int ii=0;ii<4;ii++) sv[ii]=s_arr[tid+ii*256];
    float e[4]; float ls=0.f;
    #pragma unroll
    for (int ii=0;ii<4;ii++){ e[ii]=__builtin_amdgcn_exp2f(sv[ii]); ls+=e[ii]; }
    #pragma unroll
    for (int off=32;off;off>>=1) ls += __shfl_xor(ls,off);
    if (lane==0) reds[wave]=ls;
    __syncthreads();
    const float invS = fast_rcp(reds[0]+reds[1]+reds[2]+reds[3]);
    #pragma unroll
    for (int ii=0;ii<4;ii++) s_arr[tid+ii*256]=e[ii];
    __syncthreads();

    // weighted pool from register-resident o — packed fp16 (v_pk_fma_f16)
    half4_t acch = {(_Float16)0.f,(_Float16)0.f,(_Float16)0.f,(_Float16)0.f};
    #pragma unroll
    for (int i=0;i<16;i++){
        _Float16 eh = (_Float16)s_arr[wave*256 + i*16 + col];
        half4_t evv = {eh,eh,eh,eh};
        acch += oreg[i]*evv;
    }
    {
        union { half4_t h; unsigned u[2]; } au, bu;
        au.h = acch;
        #pragma unroll
        for (int off=1;off<16;off<<=1){
            bu.u[0] = __shfl_xor(au.u[0], off);
            bu.u[1] = __shfl_xor(au.u[1], off);
            au.h += bu.h;
        }
        if (col==0){
            float4_t accf;
            #pragma unroll
            for (int r=0;r<4;r++) accf[r] = (float)au.h[r];
            *(float4_t*)&fredw[wave][kg] = accf;
        }
    }
    __syncthreads();
    if (tid<16){
        float v = (fredw[0][tid]+fredw[1][tid]+fredw[2][tid]+fredw[3][tid])*invS;
        xf[(size_t)node*F3D + bp.col0 + tid] = v;
        atomicAdd(&colacc[bp.col0 + tid], v);
    }
}

// ---------------------------------------------------------------------------
// Local CSR build (edge pattern shared across the 64 graphs)
// ---------------------------------------------------------------------------
__global__ __launch_bounds__(128)
void csr_local_kernel(const int* __restrict__ ei, int epg,
                      int* __restrict__ rowstart, int* __restrict__ cols){
    __shared__ int deg[64], cur[64], rs[65];
    const int tid = threadIdx.x;
    if (tid<64) deg[tid]=0;
    __syncthreads();
    const int total = epg + 64;
    for (int e=tid;e<total;e+=128){
        int d = (e<epg)? ei[epg+e] : (e-epg);
        atomicAdd(&deg[d],1);
    }
    __syncthreads();
    if (tid<64){
        int v = deg[tid];
        int s = v;
        #pragma unroll
        for (int off=1;off<64;off<<=1){
            int t = __shfl_up(s, off);
            if (tid >= off) s += t;
        }
        rs[tid+1] = s;
        if (tid==0) rs[0]=0;
        cur[tid] = s - v;
    }
    __syncthreads();
    for (int e=tid;e<total;e+=128){
        int sN,dN;
        if (e<epg){ sN=ei[e]; dN=ei[epg+e]; } else { sN=dN=e-epg; }
        int pos = atomicAdd(&cur[dN],1);
        cols[pos]=sN;
    }
    if (tid<65) rowstart[tid]=rs[tid];
}

// ---------------------------------------------------------------------------
// GAT layer-1 node transform; SE gate recomputed in-block from column sums.
// ---------------------------------------------------------------------------
__global__ __launch_bounds__(128)
void gat_h1_kernel(const float* __restrict__ xf, const float* __restrict__ colacc,
                   const float* __restrict__ se_w1, const float* __restrict__ se_b1,
                   const float* __restrict__ se_w2, const float* __restrict__ se_b2,
                   const float* __restrict__ W,
                   const float* __restrict__ a_src, const float* __restrict__ a_dst,
                   float* __restrict__ hbuf, float* __restrict__ als, float* __restrict__ ald){
    __shared__ float cm[F3D];
    __shared__ float g1[12];
    __shared__ float xin[F3D];
    __shared__ float hs[128];
    const int node=blockIdx.x, tid=threadIdx.x;
    if (tid<F3D) cm[tid]=colacc[tid]*(1.0f/(float)N_NODES);
    __syncthreads();
    if (tid<12){
        float v=se_b1[tid];
        for (int j=0;j<F3D;j++) v += se_w1[tid*F3D+j]*cm[j];
        g1[tid]=gelu_exact(v);
    }
    __syncthreads();
    if (tid<F3D){
        float v=se_b2[tid];
        for (int m2=0;m2<12;m2++) v += se_w2[tid*12+m2]*g1[m2];
        xin[tid] = xf[(size_t)node*F3D+tid]*fast_rcp(1.0f+__expf(-v));
    }
    __syncthreads();
    float acc=0.f;
    const float* wr = W + (size_t)tid*F3D;
    #pragma unroll
    for (int j=0;j<F3D;j++) acc += wr[j]*xin[j];
    hs[tid]=acc;
    hbuf[(size_t)node*128+tid]=acc;
    __syncthreads();
    if (tid<8){
        int head=tid&3;
        const float* av = (tid<4)? a_src : a_dst;
        float s=0.f;
        for (int c=0;c<GCD;c++) s += hs[head*GCD+c]*av[head*GCD+c];
        if (tid<4) als[(size_t)node*4+head]=s;
        else       ald[(size_t)node*4+head]=s;
    }
}

// ---------------------------------------------------------------------------
// Fused GAT tail: gather1 + gat_h2 + logits2 + gather2 + pool + FC.
// One block per graph (64 nodes); local CSR; gate recomputed in-block.
// ---------------------------------------------------------------------------
__global__ __launch_bounds__(512)
void gat_tail_kernel(const int* __restrict__ rowstart, const int* __restrict__ cols,
                     const float* __restrict__ als, const float* __restrict__ ald,
                     const float* __restrict__ hbuf,
                     const float* __restrict__ bias1,
                     const float* __restrict__ bn1_g, const float* __restrict__ bn1_b,
                     const float* __restrict__ bn1_m, const float* __restrict__ bn1_v,
                     const float* __restrict__ xf, const float* __restrict__ colacc,
                     const float* __restrict__ se_w1, const float* __restrict__ se_b1,
                     const float* __restrict__ se_w2, const float* __restrict__ se_b2,
                     const float* __restrict__ skip_w, const float* __restrict__ skip_b,
                     const float* __restrict__ W2,
                     const float* __restrict__ asrc2, const float* __restrict__ adst2,
                     const float* __restrict__ bias2,
                     const float* __restrict__ bn2_g, const float* __restrict__ bn2_b,
                     const float* __restrict__ bn2_m, const float* __restrict__ bn2_v,
                     const float* __restrict__ fc_w, const float* __restrict__ fc_b,
                     float* __restrict__ out)
{
    __shared__ float hb[64*128];
    __shared__ float xh[64*48];
    __shared__ float h1l[64*32];
    __shared__ float a1s[256], a1d[256], a2s[256], a2d[256];
    __shared__ float skw[32*48];
    __shared__ float poolv[32];
    __shared__ float cm[F3D], g1[12], gate_sh[F3D];

    const int g = blockIdx.x;
    const int tid = threadIdx.x;
    const int n0 = g*NPG;

    if (tid<F3D) cm[tid]=colacc[tid]*(1.0f/(float)N_NODES);
    __syncthreads();
    if (tid<12){
        float v=se_b1[tid];
        for (int j=0;j<F3D;j++) v += se_w1[tid*F3D+j]*cm[j];
        g1[tid]=gelu_exact(v);
    }
    __syncthreads();
    if (tid<F3D){
        float v=se_b2[tid];
        for (int m2=0;m2<12;m2++) v += se_w2[tid*12+m2]*g1[m2];
        gate_sh[tid]=fast_rcp(1.0f+__expf(-v));
    }
    __syncthreads();

    for (int i=tid;i<64*128;i+=512) hb[i] = hbuf[(size_t)n0*128 + i];
    for (int i=tid;i<64*48;i+=512)  xh[i] = xf[(size_t)n0*F3D + i] * gate_sh[i%F3D];
    for (int i=tid;i<32*48;i+=512)  skw[i] = skip_w[i];
    if (tid<256){ a1s[tid]=als[n0*4+tid]; a1d[tid]=ald[n0*4+tid]; }
    __syncthreads();

    for (int p=0;p<4;p++){
        const int nl = p*16 + (tid>>5);
        const int c  = tid&31;
        const float4 ad = *(const float4*)&a1d[nl*4];
        float m0=0,m1=0,m2=0,m3=0,d0=0,d1=0,d2=0,d3=0;
        const int s0=rowstart[nl], s1=rowstart[nl+1];
        for (int e=s0;e<s1;e++){
            const int sl = cols[e];
            const float4 as=*(const float4*)&a1s[sl*4];
            float e0=as.x+ad.x; e0=e0>0.f?e0:0.2f*e0; float w0=__expf(e0);
            float e1=as.y+ad.y; e1=e1>0.f?e1:0.2f*e1; float w1=__expf(e1);
            float e2=as.z+ad.z; e2=e2>0.f?e2:0.2f*e2; float w2=__expf(e2);
            float e3=as.w+ad.w; e3=e3>0.f?e3:0.2f*e3; float w3=__expf(e3);
            const float* hr=&hb[sl*128];
            m0+=w0*hr[c]; m1+=w1*hr[32+c]; m2+=w2*hr[64+c]; m3+=w3*hr[96+c];
            d0+=w0; d1+=w1; d2+=w2; d3+=w3;
        }
        float acc = 0.25f*(m0*fast_rcp(d0)+m1*fast_rcp(d1)+m2*fast_rcp(d2)+m3*fast_rcp(d3)) + bias1[c];
        acc = (acc-bn1_m[c])*rsqrtf(bn1_v[c]+BN_EPS)*bn1_g[c]+bn1_b[c];
        float sk = skip_b[c];
        const float* xr=&xh[nl*F3D];
        #pragma unroll
        for (int j=0;j<F3D;j++) sk += xr[j]*skw[c*F3D+j];
        h1l[nl*32+c]=gelu_exact(acc+sk);
    }
    __syncthreads();

    for (int i=tid;i<64*128;i+=512){
        const int nl=i>>7, r=i&127;
        const float4* h1r=(const float4*)&h1l[nl*32];
        const float4* wr =(const float4*)&W2[r*32];
        float acc=0.f;
        #pragma unroll
        for (int j=0;j<8;j++){
            float4 a=h1r[j], b=wr[j];
            acc += a.x*b.x + a.y*b.y + a.z*b.z + a.w*b.w;
        }
        hb[i]=acc;
    }
    __syncthreads();

    {
        const int which = tid>>8;
        const int idx = tid&255;
        const int nl=idx>>2, h=idx&3;
        const float* av = which? &adst2[h*32] : &asrc2[h*32];
        const float* hr = &hb[nl*128 + h*32];
        float s=0.f;
        #pragma unroll
        for (int c=0;c<32;c++) s += hr[c]*av[c];
        if (which) a2d[idx]=s; else a2s[idx]=s;
    }
    __syncthreads();

    for (int p=0;p<4;p++){
        const int nl = p*16 + (tid>>5);
        const int c  = tid&31;
        const float4 ad = *(const float4*)&a2d[nl*4];
        float m0=0,m1=0,m2=0,m3=0,d0=0,d1=0,d2=0,d3=0;
        const int s0=rowstart[nl], s1=rowstart[nl+1];
        for (int e=s0;e<s1;e++){
            const int sl = cols[e];
            const float4 as=*(const float4*)&a2s[sl*4];
            float e0=as.x+ad.x; e0=e0>0.f?e0:0.2f*e0; float w0=__expf(e0);
            float e1=as.y+ad.y; e1=e1>0.f?e1:0.2f*e1; float w1=__expf(e1);
            float e2=as.z+ad.z; e2=e2>0.f?e2:0.2f*e2; float w2=__expf(e2);
            float e3=as.w+ad.w; e3=e3>0.f?e3:0.2f*e3; float w3=__expf(e3);
            const float* hr=&hb[sl*128];
            m0+=w0*hr[c]; m1+=w1*hr[32+c]; m2+=w2*hr[64+c]; m3+=w3*hr[96+c];
            d0+=w0; d1+=w1; d2+=w2; d3+=w3;
        }
        float acc = 0.25f*(m0*fast_rcp(d0)+m1*fast_rcp(d1)+m2*fast_rcp(d2)+m3*fast_rcp(d3)) + bias2[c];
        acc = (acc-bn2_m[c])*rsqrtf(bn2_v[c]+BN_EPS)*bn2_g[c]+bn2_b[c];
        float v = acc + h1l[nl*32+c];
        xh[nl*32+c]=gelu_exact(v);
    }
    __syncthreads();

    if (tid<32){
        float s=0.f;
        for (int n=0;n<NPG;n++) s += xh[n*32+tid];
        poolv[tid]=s*(1.0f/(float)NPG);
    }
    __syncthreads();
    if (tid<2){
        float o=fc_b[tid];
        #pragma unroll
        for (int c=0;c<GCD;c++) o += poolv[c]*fc_w[tid*GCD+c];
        out[g*2+tid]=o;
    }
}

// ---------------------------------------------------------------------------
extern "C" void kernel_launch(void* const* d_in, const int* in_sizes, int n_in,
                              void* d_out, int out_size, void* d_ws, size_t ws_size,
                              hipStream_t stream){
    const float* x = (const float*)d_in[0];
    const int* ei = (const int*)d_in[1];
    const int epg = in_sizes[1]/2;

    float* ws = (float*)d_ws;
    float* xf      = ws;                                   // [4096,48]
    float* colacc  = xf + (size_t)N_NODES*F3D;             // 64
    float* hbuf    = colacc + 64;                          // [4096,128]
    float* als     = hbuf + (size_t)N_NODES*128;           // [4096,4]
    float* ald     = als + (size_t)N_NODES*4;              // [4096,4]
    int*   rowstart = (int*)(ald + (size_t)N_NODES*4);     // [65]
    int*   cols     = rowstart + 80;                       // [epg+64]

    auto P = [&](int i){ return (const float*)d_in[i]; };

    (void)hipMemsetAsync(colacc, 0, 64*sizeof(float), stream);
    csr_local_kernel<<<1,128,0,stream>>>(ei,epg,rowstart,cols);

    BranchParams bps[3];
    const int Ks[3] = {3,5,7};
    for (int b=0;b<3;b++){
        int base = 2 + b*10;
        bps[b].conv_w = P(base+0); bps[b].conv_b = P(base+1);
        bps[b].bn_g = P(base+2);   bps[b].bn_b = P(base+3);
        bps[b].bn_m = P(base+4);   bps[b].bn_v = P(base+5);
        bps[b].aw1 = P(base+6);    bps[b].ab1 = P(base+7);
        bps[b].aw2 = P(base+8);    bps[b].ab2 = P(base+9);
        bps[b].K = Ks[b]; bps[b].col0 = b*TCH;
    }
    branch_kernel<<<dim3(N_NODES,3),256,0,stream>>>(x, bps[0], bps[1], bps[2], xf, colacc);

    gat_h1_kernel<<<N_NODES,128,0,stream>>>(xf,colacc,P(32),P(33),P(34),P(35),
                                            P(36),P(37),P(38),hbuf,als,ald);

    gat_tail_kernel<<<NGRAPH,512,0,stream>>>(
        rowstart,cols,als,ald,hbuf,
        P(39),P(40),P(41),P(42),P(43),
        xf,colacc,P(32),P(33),P(34),P(35),
        P(44),P(45),
        P(46),P(47),P(48),P(49),P(50),P(51),P(52),P(53),
        P(54),P(55),(float*)d_out);
}

// Round 11
// 231.450 us; speedup vs baseline: 1.0417x; 1.0294x over previous
//
#include <hip/hip_runtime.h>
#include <math.h>

#define N_NODES 4096
#define T_LEN 1000
#define TCH 16
#define AHD 32
#define F3D 48
#define GCD 32
#define NPG 64
#define NGRAPH 64
#define BN_EPS 1e-5f

typedef _Float16 half4_t __attribute__((ext_vector_type(4)));
typedef float float4_t __attribute__((ext_vector_type(4)));

__device__ __forceinline__ float fast_rcp(float x){ return __builtin_amdgcn_rcpf(x); }
__device__ __forceinline__ float gelu_exact(float v){
    return 0.5f*v*(1.0f+erff(v*0.70710678118654752f));
}

struct BranchParams {
    const float* conv_w; const float* conv_b;
    const float* bn_g; const float* bn_b; const float* bn_m; const float* bn_v;
    const float* aw1; const float* ab1; const float* aw2; const float* ab2;
    int K; int col0;
};

// ---------------------------------------------------------------------------
// Unified branch kernel (round-10 config, unchanged): conv-as-MFMA ->
// sigmoid-form GELU (pair-shared rcp) -> einsum MFMA with 2*log2e prefolded ->
// exp2-tanh (pair-shared rcp) -> block softmax (no max-sub; exp2 domain) ->
// packed-fp16 register pool. ~90% of the trans-pipe roofline.
// ---------------------------------------------------------------------------
__global__ __launch_bounds__(256)
void branch_kernel(const float* __restrict__ x,
                   BranchParams bp0, BranchParams bp1, BranchParams bp2,
                   float* __restrict__ xf, float* __restrict__ colacc)
{
    __shared__ __align__(16) float xs_f[1056];
    __shared__ __align__(8)  _Float16 xsc[4][1048];
    __shared__ __align__(8)  _Float16 cws16[256];
    __shared__ float s_arr[1024];
    __shared__ __align__(16) float shiftc[16];
    __shared__ float scl[16];
    __shared__ float reds[4];
    __shared__ __align__(16) float fredw[4][16];

    const BranchParams bp = (blockIdx.y==0)? bp0 : (blockIdx.y==1)? bp1 : bp2;
    const int tid = threadIdx.x;
    const int node = blockIdx.x;
    const int K = bp.K;
    const float* xrow = x + (size_t)node*T_LEN;

    for (int j=tid;j<1056;j+=256){
        int q = j-8;
        xs_f[j] = (q>=0 && q<T_LEN)? xrow[q] : 0.f;
    }
    if (tid<16){
        float s = bp.bn_g[tid]*rsqrtf(bp.bn_v[tid]+BN_EPS);
        scl[tid]=s;
        shiftc[tid] = (bp.conv_b[tid]-bp.bn_m[tid])*s + bp.bn_b[tid];
    }
    __syncthreads();
    for (int j=tid;j<1048;j+=256){
        xsc[0][j]=(_Float16)xs_f[j];
        xsc[1][j]=(_Float16)xs_f[j+1];
        xsc[2][j]=(_Float16)xs_f[j+2];
        xsc[3][j]=(_Float16)xs_f[j+3];
    }
    {
        int ch=tid>>4, tap=tid&15;
        cws16[tid] = (tap<K)? (_Float16)(bp.conv_w[ch*K+tap]*scl[ch]) : (_Float16)0.f;
    }
    __syncthreads();

    const int lane = tid&63, wave = tid>>6;
    const int col  = lane&15;
    const int kg   = (lane>>4)<<2;

    const half4_t  acw = *(const half4_t*)&cws16[col*16+kg];
    const float4_t csh = *(const float4_t*)&shiftc[kg];

    const float TWO_LOG2E = 2.8853900817779268f;
    const float LOG2E = 1.4426950408889634f;

    float4_t wr0 = *(const float4_t*)&bp.aw1[(size_t)col*TCH + kg];
    float4_t wr1 = *(const float4_t*)&bp.aw1[(size_t)(col+16)*TCH + kg];
    half4_t a0,a1;
    #pragma unroll
    for (int r=0;r<4;r++){ a0[r]=(_Float16)(wr0[r]*TWO_LOG2E); a1[r]=(_Float16)(wr1[r]*TWO_LOG2E); }
    float4_t c0  = *(const float4_t*)&bp.ab1[kg];
    float4_t c1  = *(const float4_t*)&bp.ab1[16+kg];
    #pragma unroll
    for (int r=0;r<4;r++){ c0[r]*=TWO_LOG2E; c1[r]*=TWO_LOG2E; }
    float4_t w20 = *(const float4_t*)&bp.aw2[kg];
    float4_t w21 = *(const float4_t*)&bp.aw2[16+kg];
    #pragma unroll
    for (int r=0;r<4;r++){ w20[r]*=LOG2E; w21[r]*=LOG2E; }
    const float b2v = bp.ab2[0]*LOG2E;
    const float w2sum8 = w20[0]+w20[1]+w20[2]+w20[3]+w21[0]+w21[1]+w21[2]+w21[3];

    const float C1GE = -2.30220818f;
    const float C2GE = -0.10294324f;

    const int abase = 8 + wave*256 + col + kg - K/2;
    const int sh = abase & 3;
    const _Float16* xw_base = &xsc[sh][abase - sh];

    half4_t oreg[16];
    #pragma unroll
    for (int i=0;i<16;i++){
        half4_t xw = *(const half4_t*)(xw_base + i*16);
        float4_t d = __builtin_amdgcn_mfma_f32_16x16x16f16(acw, xw, csh, 0,0,0);

        float vv[4], dd[4];
        #pragma unroll
        for (int r=0;r<4;r++){
            float v = d[r];
            vv[r] = v;
            float t = fmaxf(v, -9.0f);
            float u = t*t;
            float pq = fmaf(C2GE, u, C1GE);
            dd[r] = __builtin_amdgcn_exp2f(pq*t) + 1.0f;
        }
        half4_t ob;
        {
            float rp0 = fast_rcp(dd[0]*dd[1]);
            float rp1 = fast_rcp(dd[2]*dd[3]);
            ob[0] = (_Float16)(vv[0]*(dd[1]*rp0));
            ob[1] = (_Float16)(vv[1]*(dd[0]*rp0));
            ob[2] = (_Float16)(vv[2]*(dd[3]*rp1));
            ob[3] = (_Float16)(vv[3]*(dd[2]*rp1));
        }
        oreg[i] = ob;

        float4_t h0 = __builtin_amdgcn_mfma_f32_16x16x16f16(a0, ob, c0, 0,0,0);
        float4_t h1 = __builtin_amdgcn_mfma_f32_16x16x16f16(a1, ob, c1, 0,0,0);
        float accr = 0.f;
        #pragma unroll
        for (int r=0;r<4;r++){
            float e0 = __builtin_amdgcn_exp2f(h0[r]) + 1.0f;
            float e1 = __builtin_amdgcn_exp2f(h1[r]) + 1.0f;
            float rp = fast_rcp(e0*e1);
            accr = fmaf(w20[r], e1*rp, accr);
            accr = fmaf(w21[r], e0*rp, accr);
        }
        float part = fmaf(-2.0f, accr, w2sum8);
        part += __shfl_xor(part,16);
        part += __shfl_xor(part,32);
        const int pos0 = wave*256 + i*16;
        if (lane<16) s_arr[pos0+lane] = (pos0+lane < T_LEN)? (part + b2v) : -INFINITY;
    }
    __syncthreads();

    float sv[4];
    #pragma unroll
    for (int ii=0;ii<4;ii++) sv[ii]=s_arr[tid+ii*256];
    float e[4]; float ls=0.f;
    #pragma unroll
    for (int ii=0;ii<4;ii++){ e[ii]=__builtin_amdgcn_exp2f(sv[ii]); ls+=e[ii]; }
    #pragma unroll
    for (int off=32;off;off>>=1) ls += __shfl_xor(ls,off);
    if (lane==0) reds[wave]=ls;
    __syncthreads();
    const float invS = fast_rcp(reds[0]+reds[1]+reds[2]+reds[3]);
    #pragma unroll
    for (int ii=0;ii<4;ii++) s_arr[tid+ii*256]=e[ii];
    __syncthreads();

    half4_t acch = {(_Float16)0.f,(_Float16)0.f,(_Float16)0.f,(_Float16)0.f};
    #pragma unroll
    for (int i=0;i<16;i++){
        _Float16 eh = (_Float16)s_arr[wave*256 + i*16 + col];
        half4_t evv = {eh,eh,eh,eh};
        acch += oreg[i]*evv;
    }
    {
        union { half4_t h; unsigned u[2]; } au, bu;
        au.h = acch;
        #pragma unroll
        for (int off=1;off<16;off<<=1){
            bu.u[0] = __shfl_xor(au.u[0], off);
            bu.u[1] = __shfl_xor(au.u[1], off);
            au.h += bu.h;
        }
        if (col==0){
            float4_t accf;
            #pragma unroll
            for (int r=0;r<4;r++) accf[r] = (float)au.h[r];
            *(float4_t*)&fredw[wave][kg] = accf;
        }
    }
    __syncthreads();
    if (tid<16){
        float v = (fredw[0][tid]+fredw[1][tid]+fredw[2][tid]+fredw[3][tid])*invS;
        xf[(size_t)node*F3D + bp.col0 + tid] = v;
        atomicAdd(&colacc[bp.col0 + tid], v);
    }
}

// ---------------------------------------------------------------------------
// Local CSR build (edge pattern shared across the 64 graphs)
// ---------------------------------------------------------------------------
__global__ __launch_bounds__(128)
void csr_local_kernel(const int* __restrict__ ei, int epg,
                      int* __restrict__ rowstart, int* __restrict__ cols){
    __shared__ int deg[64], cur[64], rs[65];
    const int tid = threadIdx.x;
    if (tid<64) deg[tid]=0;
    __syncthreads();
    const int total = epg + 64;
    for (int e=tid;e<total;e+=128){
        int d = (e<epg)? ei[epg+e] : (e-epg);
        atomicAdd(&deg[d],1);
    }
    __syncthreads();
    if (tid<64){
        int v = deg[tid];
        int s = v;
        #pragma unroll
        for (int off=1;off<64;off<<=1){
            int t = __shfl_up(s, off);
            if (tid >= off) s += t;
        }
        rs[tid+1] = s;
        if (tid==0) rs[0]=0;
        cur[tid] = s - v;
    }
    __syncthreads();
    for (int e=tid;e<total;e+=128){
        int sN,dN;
        if (e<epg){ sN=ei[e]; dN=ei[epg+e]; } else { sN=dN=e-epg; }
        int pos = atomicAdd(&cur[dN],1);
        cols[pos]=sN;
    }
    if (tid<65) rowstart[tid]=rs[tid];
}

// ---------------------------------------------------------------------------
// Fully fused GAT: SE gate + W1 transform + logits1 + gather1 + W2 transform
// + logits2 + gather2 + pool + FC. One block per graph; everything block-local.
// ---------------------------------------------------------------------------
__global__ __launch_bounds__(512)
void gat_tail_kernel(const int* __restrict__ rowstart, const int* __restrict__ cols,
                     const float* __restrict__ xf, const float* __restrict__ colacc,
                     const float* __restrict__ se_w1, const float* __restrict__ se_b1,
                     const float* __restrict__ se_w2, const float* __restrict__ se_b2,
                     const float* __restrict__ W1,
                     const float* __restrict__ asrc1, const float* __restrict__ adst1,
                     const float* __restrict__ bias1,
                     const float* __restrict__ bn1_g, const float* __restrict__ bn1_b,
                     const float* __restrict__ bn1_m, const float* __restrict__ bn1_v,
                     const float* __restrict__ skip_w, const float* __restrict__ skip_b,
                     const float* __restrict__ W2,
                     const float* __restrict__ asrc2, const float* __restrict__ adst2,
                     const float* __restrict__ bias2,
                     const float* __restrict__ bn2_g, const float* __restrict__ bn2_b,
                     const float* __restrict__ bn2_m, const float* __restrict__ bn2_v,
                     const float* __restrict__ fc_w, const float* __restrict__ fc_b,
                     float* __restrict__ out)
{
    __shared__ float hb[64*128];      // h-transform fragments (layer 1, then layer 2)
    __shared__ float xh[64*48];       // xf*gate; tail reused as h2 (64*32)
    __shared__ float h1l[64*32];
    __shared__ float a1s[256], a1d[256], a2s[256], a2d[256];
    __shared__ float skw[32*48];
    __shared__ float poolv[32];
    __shared__ float cm[F3D], g1[12], gate_sh[F3D];

    const int g = blockIdx.x;
    const int tid = threadIdx.x;
    const int n0 = g*NPG;

    // ---- SE gate (recomputed per block from column sums) ----
    if (tid<F3D) cm[tid]=colacc[tid]*(1.0f/(float)N_NODES);
    __syncthreads();
    if (tid<12){
        float v=se_b1[tid];
        for (int j=0;j<F3D;j++) v += se_w1[tid*F3D+j]*cm[j];
        g1[tid]=gelu_exact(v);
    }
    __syncthreads();
    if (tid<F3D){
        float v=se_b2[tid];
        for (int m2=0;m2<12;m2++) v += se_w2[tid*12+m2]*g1[m2];
        gate_sh[tid]=fast_rcp(1.0f+__expf(-v));
    }
    __syncthreads();

    // ---- stage xf*gate and skip weights ----
    for (int i=tid;i<64*48;i+=512)  xh[i] = xf[(size_t)n0*F3D + i] * gate_sh[i%F3D];
    for (int i=tid;i<32*48;i+=512)  skw[i] = skip_w[i];
    __syncthreads();

    // ---- GAT layer-1 transform: hb[n][r] = xh[n] . W1[r]  (48-dot) ----
    for (int i=tid;i<64*128;i+=512){
        const int nl=i>>7, r=i&127;
        const float4* xr=(const float4*)&xh[nl*48];
        const float4* wr=(const float4*)&W1[r*48];
        float acc=0.f;
        #pragma unroll
        for (int j=0;j<12;j++){
            float4 a=xr[j], b=wr[j];
            acc += a.x*b.x + a.y*b.y + a.z*b.z + a.w*b.w;
        }
        hb[i]=acc;
    }
    __syncthreads();

    // ---- logits1 ----
    {
        const int which = tid>>8;
        const int idx = tid&255;
        const int nl=idx>>2, h=idx&3;
        const float* av = which? &adst1[h*32] : &asrc1[h*32];
        const float* hr = &hb[nl*128 + h*32];
        float s=0.f;
        #pragma unroll
        for (int c=0;c<32;c++) s += hr[c]*av[c];
        if (which) a1d[idx]=s; else a1s[idx]=s;
    }
    __syncthreads();

    // ---- gather1 + BN1 + skip + GELU -> h1l ----
    for (int p=0;p<4;p++){
        const int nl = p*16 + (tid>>5);
        const int c  = tid&31;
        const float4 ad = *(const float4*)&a1d[nl*4];
        float m0=0,m1=0,m2=0,m3=0,d0=0,d1=0,d2=0,d3=0;
        const int s0=rowstart[nl], s1=rowstart[nl+1];
        for (int e=s0;e<s1;e++){
            const int sl = cols[e];
            const float4 as=*(const float4*)&a1s[sl*4];
            float e0=as.x+ad.x; e0=e0>0.f?e0:0.2f*e0; float w0=__expf(e0);
            float e1=as.y+ad.y; e1=e1>0.f?e1:0.2f*e1; float w1=__expf(e1);
            float e2=as.z+ad.z; e2=e2>0.f?e2:0.2f*e2; float w2=__expf(e2);
            float e3=as.w+ad.w; e3=e3>0.f?e3:0.2f*e3; float w3=__expf(e3);
            const float* hr=&hb[sl*128];
            m0+=w0*hr[c]; m1+=w1*hr[32+c]; m2+=w2*hr[64+c]; m3+=w3*hr[96+c];
            d0+=w0; d1+=w1; d2+=w2; d3+=w3;
        }
        float acc = 0.25f*(m0*fast_rcp(d0)+m1*fast_rcp(d1)+m2*fast_rcp(d2)+m3*fast_rcp(d3)) + bias1[c];
        acc = (acc-bn1_m[c])*rsqrtf(bn1_v[c]+BN_EPS)*bn1_g[c]+bn1_b[c];
        float sk = skip_b[c];
        const float* xr=&xh[nl*F3D];
        #pragma unroll
        for (int j=0;j<F3D;j++) sk += xr[j]*skw[c*F3D+j];
        h1l[nl*32+c]=gelu_exact(acc+sk);
    }
    __syncthreads();

    // ---- GAT layer-2 transform: hb[n][r] = h1l[n] . W2[r]  (32-dot) ----
    for (int i=tid;i<64*128;i+=512){
        const int nl=i>>7, r=i&127;
        const float4* h1r=(const float4*)&h1l[nl*32];
        const float4* wr =(const float4*)&W2[r*32];
        float acc=0.f;
        #pragma unroll
        for (int j=0;j<8;j++){
            float4 a=h1r[j], b=wr[j];
            acc += a.x*b.x + a.y*b.y + a.z*b.z + a.w*b.w;
        }
        hb[i]=acc;
    }
    __syncthreads();

    // ---- logits2 ----
    {
        const int which = tid>>8;
        const int idx = tid&255;
        const int nl=idx>>2, h=idx&3;
        const float* av = which? &adst2[h*32] : &asrc2[h*32];
        const float* hr = &hb[nl*128 + h*32];
        float s=0.f;
        #pragma unroll
        for (int c=0;c<32;c++) s += hr[c]*av[c];
        if (which) a2d[idx]=s; else a2s[idx]=s;
    }
    __syncthreads();

    // ---- gather2 + BN2 + residual + GELU -> h2 (reuse xh) ----
    for (int p=0;p<4;p++){
        const int nl = p*16 + (tid>>5);
        const int c  = tid&31;
        const float4 ad = *(const float4*)&a2d[nl*4];
        float m0=0,m1=0,m2=0,m3=0,d0=0,d1=0,d2=0,d3=0;
        const int s0=rowstart[nl], s1=rowstart[nl+1];
        for (int e=s0;e<s1;e++){
            const int sl = cols[e];
            const float4 as=*(const float4*)&a2s[sl*4];
            float e0=as.x+ad.x; e0=e0>0.f?e0:0.2f*e0; float w0=__expf(e0);
            float e1=as.y+ad.y; e1=e1>0.f?e1:0.2f*e1; float w1=__expf(e1);
            float e2=as.z+ad.z; e2=e2>0.f?e2:0.2f*e2; float w2=__expf(e2);
            float e3=as.w+ad.w; e3=e3>0.f?e3:0.2f*e3; float w3=__expf(e3);
            const float* hr=&hb[sl*128];
            m0+=w0*hr[c]; m1+=w1*hr[32+c]; m2+=w2*hr[64+c]; m3+=w3*hr[96+c];
            d0+=w0; d1+=w1; d2+=w2; d3+=w3;
        }
        float acc = 0.25f*(m0*fast_rcp(d0)+m1*fast_rcp(d1)+m2*fast_rcp(d2)+m3*fast_rcp(d3)) + bias2[c];
        acc = (acc-bn2_m[c])*rsqrtf(bn2_v[c]+BN_EPS)*bn2_g[c]+bn2_b[c];
        float v = acc + h1l[nl*32+c];
        xh[nl*32+c]=gelu_exact(v);
    }
    __syncthreads();

    // ---- pool + FC ----
    if (tid<32){
        float s=0.f;
        for (int n=0;n<NPG;n++) s += xh[n*32+tid];
        poolv[tid]=s*(1.0f/(float)NPG);
    }
    __syncthreads();
    if (tid<2){
        float o=fc_b[tid];
        #pragma unroll
        for (int c=0;c<GCD;c++) o += poolv[c]*fc_w[tid*GCD+c];
        out[g*2+tid]=o;
    }
}

// ---------------------------------------------------------------------------
extern "C" void kernel_launch(void* const* d_in, const int* in_sizes, int n_in,
                              void* d_out, int out_size, void* d_ws, size_t ws_size,
                              hipStream_t stream){
    const float* x = (const float*)d_in[0];
    const int* ei = (const int*)d_in[1];
    const int epg = in_sizes[1]/2;

    float* ws = (float*)d_ws;
    float* xf      = ws;                                   // [4096,48]
    float* colacc  = xf + (size_t)N_NODES*F3D;             // 64
    int*   rowstart = (int*)(colacc + 64);                 // [65]
    int*   cols     = rowstart + 80;                       // [epg+64]

    auto P = [&](int i){ return (const float*)d_in[i]; };

    (void)hipMemsetAsync(colacc, 0, 64*sizeof(float), stream);
    csr_local_kernel<<<1,128,0,stream>>>(ei,epg,rowstart,cols);

    BranchParams bps[3];
    const int Ks[3] = {3,5,7};
    for (int b=0;b<3;b++){
        int base = 2 + b*10;
        bps[b].conv_w = P(base+0); bps[b].conv_b = P(base+1);
        bps[b].bn_g = P(base+2);   bps[b].bn_b = P(base+3);
        bps[b].bn_m = P(base+4);   bps[b].bn_v = P(base+5);
        bps[b].aw1 = P(base+6);    bps[b].ab1 = P(base+7);
        bps[b].aw2 = P(base+8);    bps[b].ab2 = P(base+9);
        bps[b].K = Ks[b]; bps[b].col0 = b*TCH;
    }
    branch_kernel<<<dim3(N_NODES,3),256,0,stream>>>(x, bps[0], bps[1], bps[2], xf, colacc);

    gat_tail_kernel<<<NGRAPH,512,0,stream>>>(
        rowstart,cols,
        xf,colacc,P(32),P(33),P(34),P(35),
        P(36),P(37),P(38),
        P(39),P(40),P(41),P(42),P(43),
        P(44),P(45),
        P(46),P(47),P(48),P(49),P(50),P(51),P(52),P(53),
        P(54),P(55),(float*)d_out);
}